// Round 2
// baseline (575.222 us; speedup 1.0000x reference)
//
#include <hip/hip_runtime.h>

// AdaConv2d as pre-pass + implicit GEMM (bf16 MFMA 16x16x32, fp32 acc).
//
// Pre-pass 1: xp[b][h'][w'][ic] bf16, h',w' in [0,58), zero-padded border.
// Pre-pass 2: wq[d][r][oc][ic] bf16 = kernel_base[oc][ic][r] * kernel_mask[d][ic][r].
// Main (v3): LDS-traffic-minimized implicit GEMM.
//   - B (weights) loaded DIRECT global->register per fragment (L2-resident, 2.3 MB total).
//   - A (pixels): the 64-pix tile always spans exactly 2 x-rows -> all 9 taps live in
//     4 padded xp rows. Stage one ic-half (232 rows x 64 ic = 29.7 KB) into LDS ONCE,
//     XOR-swizzled (slot = col16 ^ (R&7), pre-swizzled global source), then run
//     9 taps x 2 ic-subchunks BARRIER-FREE with 1-deep register prefetch of A and B.
//     3 barriers per block total (vs 36).

typedef __bf16 v8bf __attribute__((ext_vector_type(8)));
typedef float  v4f  __attribute__((ext_vector_type(4)));
typedef unsigned short v8us __attribute__((ext_vector_type(8)));

#define IC_  128
#define OC_  256
#define HH   56
#define WW_  56
#define HW_  3136
#define PW   58                      // padded spatial dim (and R-stride of the A panel)
#define XP_PER_B (PW * PW * IC_)     // 430592 elems
#define WQ_ELEMS (4 * 9 * OC_ * IC_) // 1179648 elems

__device__ __forceinline__ unsigned short f2bf(float f) {
    unsigned u = __builtin_bit_cast(unsigned, f);
    u += 0x7fffu + ((u >> 16) & 1u);    // RNE
    return (unsigned short)(u >> 16);
}

typedef __attribute__((address_space(3))) unsigned int lds_u32_t;
typedef const __attribute__((address_space(1))) unsigned int gbl_u32_t;

__device__ __forceinline__ void gload_lds16(const unsigned short* gsrc, unsigned short* ldst) {
    // dest = (wave-uniform ldst) + lane*16B; per-lane gsrc; 16B per lane.
    __builtin_amdgcn_global_load_lds((gbl_u32_t*)gsrc,
                                     (lds_u32_t*)(unsigned int)(unsigned long long)(uintptr_t)ldst,
                                     16, 0, 0);
}

// ---- pre-pass 1: x[b][ic][h][w] fp32 -> xp[b][h+1][w+1][ic] bf16, plus border zeroing ----
__global__ __launch_bounds__(256)
void transpose_pad(const float* __restrict__ x, unsigned short* __restrict__ xp)
{
    __shared__ unsigned short lt[IC_ * 58];   // [ic][w], stride 58
    const int blk = blockIdx.x;               // b*56 + h
    const int b = blk / HH, h = blk % HH;
    const int t = threadIdx.x;
    const float* xb = x + (size_t)b * IC_ * HW_ + h * WW_;
    #pragma unroll
    for (int i = 0; i < 7; ++i) {
        int e4 = t + i * 256;                 // < 1792
        int ic = e4 / 14;
        int w4 = (e4 - ic * 14) * 4;
        v4f v = *(const v4f*)&xb[ic * HW_ + w4];
        unsigned lo = (unsigned)f2bf(v[0]) | ((unsigned)f2bf(v[1]) << 16);
        unsigned hi = (unsigned)f2bf(v[2]) | ((unsigned)f2bf(v[3]) << 16);
        unsigned* dst = (unsigned*)&lt[ic * 58 + w4];
        dst[0] = lo;
        dst[1] = hi;
    }
    __syncthreads();
    unsigned short* xpb = xp + (size_t)b * XP_PER_B + (size_t)(h + 1) * PW * IC_;
    #pragma unroll
    for (int i = 0; i < 4; ++i) {
        int s = t + i * 256;
        if (s < 896) {                        // 56 w * 16 ic-groups
            int w = s >> 4, icg = s & 15;
            unsigned short v[8];
            #pragma unroll
            for (int j = 0; j < 8; ++j) v[j] = lt[(icg * 8 + j) * 58 + w];
            *(v8us*)&xpb[(w + 1) * IC_ + icg * 8] = *(const v8us*)v;
        }
    }
    // border cols w'=0 and w'=57 of this row
    if (t < 32) {
        int col = (t >> 4) * 57;              // 0 or 57
        *(v8us*)&xpb[(size_t)col * IC_ + (t & 15) * 8] = (v8us)(unsigned short)0;
    }
    // border rows h'=0 and h'=57
    if (h == 0 || h == HH - 1) {
        unsigned short* row = xp + (size_t)b * XP_PER_B + (h == 0 ? 0 : (size_t)(PW - 1) * PW * IC_);
        for (int s = t; s < 928; s += 256)
            *(v8us*)&row[(size_t)s * 8] = (v8us)(unsigned short)0;
    }
}

// ---- pre-pass 2: wq[d][r][oc][ic] = bf16(kbase[oc][ic][r] * kmask[d][ic][r]) ----
__global__ __launch_bounds__(256)
void build_weights(const float* __restrict__ kbase, const float* __restrict__ kmask,
                   unsigned short* __restrict__ wq)
{
    int t  = blockIdx.x * 256 + threadIdx.x;   // < 1179648
    int ic = t & 127;
    int oc = (t >> 7) & 255;
    int rd = t >> 15;                          // d*9 + r
    int r  = rd % 9, d = rd / 9;
    float v = kbase[oc * 1152 + ic * 9 + r] * kmask[d * 1152 + ic * 9 + r];
    wq[t] = f2bf(v);
}

// ---- main: implicit GEMM, A-panel in LDS (staged once per ic-half), B direct from L2 ----
__global__ __launch_bounds__(256, 3)
void adaconv_main(const unsigned short* __restrict__ xp,
                  const unsigned short* __restrict__ wq,
                  const int* __restrict__ demog,
                  float* __restrict__ out)
{
    // A panel, one ic-half: [R=232][ic64] bf16, 16B slots XOR-swizzled by (R&7).
    __shared__ unsigned short lds_x[232 * 64];   // 29,696 B

    const int t    = threadIdx.x;
    const int lane = t & 63;
    const int quad = lane >> 4;
    const int l15  = lane & 15;
    const int wid  = __builtin_amdgcn_readfirstlane(t >> 6);   // 0..3, oc quarter

    const int mtile = blockIdx.x;     // 0..48
    const int b     = blockIdx.y;     // 0..63
    const int p0    = mtile * 64;
    const int d     = demog[b];
    const int h0    = p0 / WW_;       // tile spans x-rows h0, h0+1 (always exactly 2)

    // per-lane A-fragment row base: for frag mi, pix = p0 + mi*16 + l15.
    // R(mi, tap) = baseR[mi] + ((dh)*PW + dw);  R in [0, 232)
    int baseR[4];
    #pragma unroll
    for (int mi = 0; mi < 4; ++mi) {
        int pix = p0 + mi * 16 + l15;
        int hh  = pix / WW_;
        int wwp = pix - hh * WW_;
        baseR[mi] = (hh - h0 + 1) * PW + (wwp + 1);
    }

    // staging source permutation (inverse swizzle): lane l stages LDS slot
    // (R = k*8 + (l>>3), col = l&7) <- global col (l&7) ^ (l>>3).  (R&7 == l>>3 since k*8)
    const int olane = ((lane >> 3) << 7) + ((((lane & 7) ^ (lane >> 3))) << 3);  // elems

    // per-lane B fragment bases: oc = wid*64 + ni*16 + l15, k-slot = quad*8
    const unsigned short* bbase[4];
    #pragma unroll
    for (int ni = 0; ni < 4; ++ni)
        bbase[ni] = wq + (size_t)d * 9 * OC_ * IC_ + (size_t)(wid * 64 + ni * 16 + l15) * IC_ + quad * 8;

    v4f acc[4][4];
    #pragma unroll
    for (int mi = 0; mi < 4; ++mi)
        #pragma unroll
        for (int ni = 0; ni < 4; ++ni)
            acc[mi][ni] = (v4f)0.0f;

    int tAq[4];    // per-tap swizzled A base addresses (bytes), quad folded in
    v8us au[2][4], bu[2][4];

    #define SETTAP(r)                                                          \
        do { const int offR_ = ((r) / 3 - 1) * PW + ((r) % 3 - 1);             \
            _Pragma("unroll") for (int mi = 0; mi < 4; ++mi) {                 \
                int R_ = baseR[mi] + offR_;                                    \
                tAq[mi] = (R_ << 7) + (((R_ & 7) ^ quad) << 4);                \
            } } while (0)

    #define LOADA(buf, il)                                                     \
        do { _Pragma("unroll") for (int mi = 0; mi < 4; ++mi)                  \
            au[buf][mi] = *(const v8us*)((const char*)lds_x + (tAq[mi] ^ ((il) << 6))); \
        } while (0)

    #define LOADB(buf, r, il)                                                  \
        do { _Pragma("unroll") for (int ni = 0; ni < 4; ++ni)                  \
            bu[buf][ni] = *(const v8us*)(bbase[ni] + (r) * (OC_ * IC_) + icofs + (il) * 32); \
        } while (0)

    #pragma unroll
    for (int half = 0; half < 2; ++half) {
        const unsigned short* xph = xp + (size_t)b * XP_PER_B
                                  + (size_t)h0 * PW * IC_ + half * 64;
        if (half) __syncthreads();                  // all reads of previous half done
        for (int k = wid; k < 29; k += 4)           // 29 x 1KB, pre-swizzled source
            gload_lds16(xph + (size_t)k * 1024 + olane, lds_x + k * 512);
        __syncthreads();                            // panel staged (implicit vmcnt drain)

        const int icofs = half * 64;

        SETTAP(0);
        LOADA(0, 0);
        LOADB(0, 0, 0);

        #pragma unroll
        for (int c = 0; c < 18; ++c) {              // chunk: r = c>>1, il = c&1
            const int cur = c & 1;
            const int nc  = c + 1;
            if (nc < 18) {
                const int nr = nc >> 1, nil = nc & 1;
                if (nil == 0) SETTAP(nr);
                LOADB(cur ^ 1, nr, nil);            // global, long-latency: issue first
                LOADA(cur ^ 1, nil);                // ds_read
            }
            #pragma unroll
            for (int mi = 0; mi < 4; ++mi) {
                v8bf a = __builtin_bit_cast(v8bf, au[cur][mi]);
                #pragma unroll
                for (int ni = 0; ni < 4; ++ni) {
                    v8bf bb = __builtin_bit_cast(v8bf, bu[cur][ni]);
                    acc[mi][ni] = __builtin_amdgcn_mfma_f32_16x16x32_bf16(a, bb, acc[mi][ni], 0, 0, 0);
                }
            }
        }
    }
    #undef SETTAP
    #undef LOADA
    #undef LOADB

    // epilogue: D row = quad*4+reg (pix), col = l15 (oc)
    float* ob = out + ((size_t)b * OC_ + wid * 64) * HW_ + p0;
    #pragma unroll
    for (int ni = 0; ni < 4; ++ni) {
        #pragma unroll
        for (int mi = 0; mi < 4; ++mi) {
            float* o = ob + (size_t)(ni * 16 + l15) * HW_ + mi * 16 + quad * 4;
            *(v4f*)o = acc[mi][ni];
        }
    }
}

extern "C" void kernel_launch(void* const* d_in, const int* in_sizes, int n_in,
                              void* d_out, int out_size, void* d_ws, size_t ws_size,
                              hipStream_t stream) {
    const float* x     = (const float*)d_in[0];
    const int*   demog = (const int*)d_in[1];
    const float* kbase = (const float*)d_in[2];
    const float* kmask = (const float*)d_in[3];
    float* out = (float*)d_out;

    unsigned short* xp = (unsigned short*)d_ws;
    unsigned short* wq = xp + (size_t)64 * XP_PER_B;
    transpose_pad<<<64 * HH, 256, 0, stream>>>(x, xp);
    build_weights<<<WQ_ELEMS / 256, 256, 0, stream>>>(kbase, kmask, wq);
    adaconv_main<<<dim3(49, 64), 256, 0, stream>>>(xp, wq, demog, out);
}

// Round 3
// 420.611 us; speedup vs baseline: 1.3676x; 1.3676x over previous
//
#include <hip/hip_runtime.h>

// AdaConv2d as pre-pass + implicit GEMM (bf16 MFMA 16x16x32, fp32 acc).
//
// Main (v4): counted-vmcnt software pipeline (T3+T4), A-panel resident.
//   - A (pixels): 64-pix tile spans 2 x-rows -> 9 taps live in 4 padded xp rows.
//     Stage one ic-half (232 x 64 = 29.7 KB) in LDS, XOR-swizzled (proven in v3).
//   - B (weights): LDS, 3 buffers x 16 KB, 2-deep prefetch. Chunk c issues B(c+2);
//     top-of-chunk does raw `s_waitcnt vmcnt(4)` + `s_barrier` (NOT __syncthreads,
//     which drains vmcnt(0) and kills the pipeline). B LDS is bank-swizzled:
//     128B rows = oc-pairs, slot = ((oc&1)<<2)|quad, stored at slot^(row&7)
//     via pre-swizzled global source (rule #21: both-sides-or-neither).
//   - T5 setprio(1) around the 16-MFMA cluster; bijective XCD block swizzle.

typedef __bf16 v8bf __attribute__((ext_vector_type(8)));
typedef float  v4f  __attribute__((ext_vector_type(4)));
typedef unsigned short v8us __attribute__((ext_vector_type(8)));

#define IC_  128
#define OC_  256
#define HH   56
#define WW_  56
#define HW_  3136
#define PW   58                      // padded spatial dim
#define XP_PER_B (PW * PW * IC_)     // 430592 elems
#define WQ_ELEMS (4 * 9 * OC_ * IC_) // 1179648 elems

__device__ __forceinline__ unsigned short f2bf(float f) {
    unsigned u = __builtin_bit_cast(unsigned, f);
    u += 0x7fffu + ((u >> 16) & 1u);    // RNE
    return (unsigned short)(u >> 16);
}

typedef __attribute__((address_space(3))) unsigned int lds_u32_t;
typedef const __attribute__((address_space(1))) unsigned int gbl_u32_t;

__device__ __forceinline__ void gload_lds16(const unsigned short* gsrc, unsigned short* ldst) {
    // dest = (wave-uniform ldst) + lane*16B; per-lane gsrc; 16B per lane.
    __builtin_amdgcn_global_load_lds((gbl_u32_t*)gsrc,
                                     (lds_u32_t*)(unsigned int)(unsigned long long)(uintptr_t)ldst,
                                     16, 0, 0);
}

// ---- pre-pass 1: x[b][ic][h][w] fp32 -> xp[b][h+1][w+1][ic] bf16, plus border zeroing ----
__global__ __launch_bounds__(256)
void transpose_pad(const float* __restrict__ x, unsigned short* __restrict__ xp)
{
    __shared__ unsigned short lt[IC_ * 58];   // [ic][w], stride 58
    const int blk = blockIdx.x;               // b*56 + h
    const int b = blk / HH, h = blk % HH;
    const int t = threadIdx.x;
    const float* xb = x + (size_t)b * IC_ * HW_ + h * WW_;
    #pragma unroll
    for (int i = 0; i < 7; ++i) {
        int e4 = t + i * 256;                 // < 1792
        int ic = e4 / 14;
        int w4 = (e4 - ic * 14) * 4;
        v4f v = *(const v4f*)&xb[ic * HW_ + w4];
        unsigned lo = (unsigned)f2bf(v[0]) | ((unsigned)f2bf(v[1]) << 16);
        unsigned hi = (unsigned)f2bf(v[2]) | ((unsigned)f2bf(v[3]) << 16);
        unsigned* dst = (unsigned*)&lt[ic * 58 + w4];
        dst[0] = lo;
        dst[1] = hi;
    }
    __syncthreads();
    unsigned short* xpb = xp + (size_t)b * XP_PER_B + (size_t)(h + 1) * PW * IC_;
    #pragma unroll
    for (int i = 0; i < 4; ++i) {
        int s = t + i * 256;
        if (s < 896) {                        // 56 w * 16 ic-groups
            int w = s >> 4, icg = s & 15;
            unsigned short v[8];
            #pragma unroll
            for (int j = 0; j < 8; ++j) v[j] = lt[(icg * 8 + j) * 58 + w];
            *(v8us*)&xpb[(w + 1) * IC_ + icg * 8] = *(const v8us*)v;
        }
    }
    if (t < 32) {
        int col = (t >> 4) * 57;              // 0 or 57
        *(v8us*)&xpb[(size_t)col * IC_ + (t & 15) * 8] = (v8us)(unsigned short)0;
    }
    if (h == 0 || h == HH - 1) {
        unsigned short* row = xp + (size_t)b * XP_PER_B + (h == 0 ? 0 : (size_t)(PW - 1) * PW * IC_);
        for (int s = t; s < 928; s += 256)
            *(v8us*)&row[(size_t)s * 8] = (v8us)(unsigned short)0;
    }
}

// ---- pre-pass 2: wq[d][r][oc][ic] = bf16(kbase[oc][ic][r] * kmask[d][ic][r]) ----
__global__ __launch_bounds__(256)
void build_weights(const float* __restrict__ kbase, const float* __restrict__ kmask,
                   unsigned short* __restrict__ wq)
{
    int t  = blockIdx.x * 256 + threadIdx.x;   // < 1179648
    int ic = t & 127;
    int oc = (t >> 7) & 255;
    int rd = t >> 15;                          // d*9 + r
    int r  = rd % 9, d = rd / 9;
    float v = kbase[oc * 1152 + ic * 9 + r] * kmask[d * 1152 + ic * 9 + r];
    wq[t] = f2bf(v);
}

// ---- main: implicit GEMM, counted-vmcnt pipeline ----
__global__ __launch_bounds__(256, 2)
void adaconv_main(const unsigned short* __restrict__ xp,
                  const unsigned short* __restrict__ wq,
                  const int* __restrict__ demog,
                  float* __restrict__ out)
{
    __shared__ unsigned short panel[232 * 64];     // A ic-half panel, 29,696 B, swizzled
    __shared__ unsigned short bbuf[3][256 * 32];   // B, 3 x 16 KB, swizzled; total 78,848 B

    const int t    = threadIdx.x;
    const int lane = t & 63;
    const int quad = lane >> 4;
    const int l15  = lane & 15;
    const int wid  = __builtin_amdgcn_readfirstlane(t >> 6);   // 0..3, oc quarter

    // bijective XCD-aware remap: 3136 blocks = 8 XCDs x 392; contiguous b-runs per XCD
    const int lin = blockIdx.y * 49 + blockIdx.x;
    const int nl  = (lin & 7) * 392 + (lin >> 3);
    const int mtile = nl % 49;
    const int b     = nl / 49;

    const int p0 = mtile * 64;
    const int d  = demog[b];
    const int h0 = p0 / WW_;          // tile spans x-rows h0, h0+1 (always exactly 2)

    // A fragment row bases: frag mi, pix = p0 + mi*16 + l15; R in [0,232)
    int baseR[4];
    #pragma unroll
    for (int mi = 0; mi < 4; ++mi) {
        int pix = p0 + mi * 16 + l15;
        int hh  = pix / WW_;
        int wwp = pix - hh * WW_;
        baseR[mi] = (hh - h0 + 1) * PW + (wwp + 1);
    }

    // A staging: lane l fills LDS slot (R = k*8 + (l>>3), slot = l&7), content = global
    // col-slot (l&7)^(l>>3) (inverse swizzle; proven in v3).
    const int olane = ((lane >> 3) << 7) + (((lane & 7) ^ (lane >> 3)) << 3);  // elems
    const unsigned short* xpb = xp + (size_t)b * XP_PER_B + (size_t)h0 * PW * IC_;

    // B staging: wave w, iter j, lane l fills LDS row128 = w*8 + j*32 + (l>>3),
    // slot = l&7; content = slot' = (l&7)^(l>>3) -> oc = 2*row128 + (slot'>>2),
    // kslot = slot'&3.
    const int slotp = (lane & 7) ^ (lane >> 3);
    const int ocb   = 2 * (wid * 8 + (lane >> 3)) + (slotp >> 2);
    const unsigned short* sB = wq + (size_t)d * 9 * OC_ * IC_
                             + (size_t)ocb * IC_ + (slotp & 3) * 8;

    // B read byte offsets (constant across chunks): oc = wid*64 + ni*16 + l15,
    // row128 = oc>>1, slot = ((oc&1)<<2)|quad, swizzled ^ (row128&7).
    int bOff[4];
    #pragma unroll
    for (int ni = 0; ni < 4; ++ni) {
        int oc = wid * 64 + ni * 16 + l15;
        int r128 = oc >> 1;
        bOff[ni] = (r128 << 7) + (((((oc & 1) << 2) | quad) ^ (r128 & 7)) << 4);
    }

    v4f acc[4][4];
    #pragma unroll
    for (int mi = 0; mi < 4; ++mi)
        #pragma unroll
        for (int ni = 0; ni < 4; ++ni)
            acc[mi][ni] = (v4f)0.0f;

    int tA[4];

    #define STAGEA(half_) do {                                                  \
        const unsigned short* xph_ = xpb + (half_) * 64;                        \
        _Pragma("unroll")                                                       \
        for (int kk = 0; kk < 8; ++kk) {                                        \
            int k_ = wid + kk * 4;                                              \
            if (k_ < 29) gload_lds16(xph_ + k_ * 1024 + olane, panel + k_ * 512); \
        } } while (0)

    #define STAGEB(bufi, c_) do {                                               \
        const int r_   = ((c_) % 18) >> 1;                                      \
        const int ic0_ = ((c_) / 18) * 64 + (((c_) % 18) & 1) * 32;             \
        const unsigned short* s_ = sB + r_ * (OC_ * IC_) + ic0_;                \
        _Pragma("unroll")                                                       \
        for (int j = 0; j < 4; ++j)                                             \
            gload_lds16(s_ + j * 64 * IC_, &bbuf[bufi][wid * 512 + j * 2048]);  \
        } while (0)

    #define SETTAP(r_) do {                                                     \
        const int offR_ = ((r_) / 3 - 1) * PW + ((r_) % 3 - 1);                 \
        _Pragma("unroll")                                                       \
        for (int mi = 0; mi < 4; ++mi) {                                        \
            int R_ = baseR[mi] + offR_;                                         \
            tA[mi] = (R_ << 7) + (((R_ & 7) ^ quad) << 4);                      \
        } } while (0)

    // prologue: A half-0 + B chunks 0,1; full drain once.
    STAGEA(0);
    STAGEB(0, 0);
    STAGEB(1, 1);
    asm volatile("s_waitcnt vmcnt(0)" ::: "memory");
    __builtin_amdgcn_s_barrier();

    #pragma unroll
    for (int c = 0; c < 36; ++c) {
        if (c > 0) {
            // my chunk-c B loads (issued at c-2) must be done; only c+1's 4 may remain.
            if (c < 35) asm volatile("s_waitcnt vmcnt(4)" ::: "memory");
            else        asm volatile("s_waitcnt vmcnt(0)" ::: "memory");
            __builtin_amdgcn_s_barrier();   // raw barrier: no vmcnt(0) drain
        }
        if (c == 18) STAGEA(1);                     // restage A half-1 (panel reads done)
        if (c + 2 < 36) STAGEB((c + 2) % 3, c + 2); // 2-deep B prefetch
        if (c == 18) asm volatile("s_waitcnt vmcnt(4)" ::: "memory");  // A restage landed

        const int r   = (c % 18) >> 1;
        const int icb = (c % 18) & 1;
        if (icb == 0) SETTAP(r);

        v8us au[4], bu[4];
        #pragma unroll
        for (int mi = 0; mi < 4; ++mi)
            au[mi] = *(const v8us*)((const char*)panel + (tA[mi] ^ (icb << 6)));
        #pragma unroll
        for (int ni = 0; ni < 4; ++ni)
            bu[ni] = *(const v8us*)((const char*)bbuf[c % 3] + bOff[ni]);

        __builtin_amdgcn_s_setprio(1);
        #pragma unroll
        for (int mi = 0; mi < 4; ++mi) {
            v8bf a = __builtin_bit_cast(v8bf, au[mi]);
            #pragma unroll
            for (int ni = 0; ni < 4; ++ni) {
                v8bf bb = __builtin_bit_cast(v8bf, bu[ni]);
                acc[mi][ni] = __builtin_amdgcn_mfma_f32_16x16x32_bf16(a, bb, acc[mi][ni], 0, 0, 0);
            }
        }
        __builtin_amdgcn_s_setprio(0);
    }
    #undef STAGEA
    #undef STAGEB
    #undef SETTAP

    // epilogue: D row = quad*4+reg (pix), col = l15 (oc)
    float* ob = out + ((size_t)b * OC_ + wid * 64) * HW_ + p0;
    #pragma unroll
    for (int ni = 0; ni < 4; ++ni) {
        #pragma unroll
        for (int mi = 0; mi < 4; ++mi) {
            float* o = ob + (size_t)(ni * 16 + l15) * HW_ + mi * 16 + quad * 4;
            *(v4f*)o = acc[mi][ni];
        }
    }
}

extern "C" void kernel_launch(void* const* d_in, const int* in_sizes, int n_in,
                              void* d_out, int out_size, void* d_ws, size_t ws_size,
                              hipStream_t stream) {
    const float* x     = (const float*)d_in[0];
    const int*   demog = (const int*)d_in[1];
    const float* kbase = (const float*)d_in[2];
    const float* kmask = (const float*)d_in[3];
    float* out = (float*)d_out;

    unsigned short* xp = (unsigned short*)d_ws;
    unsigned short* wq = xp + (size_t)64 * XP_PER_B;
    transpose_pad<<<64 * HH, 256, 0, stream>>>(x, xp);
    build_weights<<<WQ_ELEMS / 256, 256, 0, stream>>>(kbase, kmask, wq);
    adaconv_main<<<dim3(49, 64), 256, 0, stream>>>(xp, wq, demog, out);
}